// Round 9
// baseline (267.201 us; speedup 1.0000x reference)
//
#include <hip/hip_runtime.h>

#define GS 64
#define BB 128
#define NN 8192
#define KK 3
#define SLICE_FLOATS (GS * GS * GS * 3)   // 786432 floats = 3 MB per b
#define B_PER_XCD 16
#define BLOCKS_PER_B 32                   // 32 chunks of 256 pts; all k per thread
#define GRID (BB * BLOCKS_PER_B)          // 4096

// ws layout:
//   [0, 32768)        : float2 partials[4096]
//   [32768, 32832)    : unsigned ctr (+pad)
//   [32832, +12288)   : refl params [K*B][8] floats: (nx,ny,nz,d, mx,my,mz,_)
//   [45120, +6144)    : quat params [K*B][4] floats: (w,vx,vy,vz) normalized
#define CTR_OFF   32768
#define REFL_OFF  32832
#define QUAT_OFF  (REFL_OFF + KK * BB * 8 * 4)

// Precompute normalized transform params (384 sets) + zero completion ctr.
__global__ void init_kernel(const float* __restrict__ plane,
                            const float* __restrict__ quat, char* ws) {
    int i = threadIdx.x;                  // 0..383 = k*BB+b
    if (i == 0) *(unsigned*)(ws + CTR_OFF) = 0u;
    if (i < KK * BB) {
        const float* pl = plane + (size_t)i * 4;
        float nx = pl[0], ny = pl[1], nz = pl[2], d = pl[3];
        float denom = nx * nx + ny * ny + nz * nz + 1e-12f;
        float inv2 = 2.0f / denom;
        float* rp = (float*)(ws + REFL_OFF) + (size_t)i * 8;
        rp[0] = nx; rp[1] = ny; rp[2] = nz; rp[3] = d;
        rp[4] = nx * inv2; rp[5] = ny * inv2; rp[6] = nz * inv2; rp[7] = 0.f;

        const float* q = quat + (size_t)i * 4;
        float qw = q[0], qx = q[1], qy = q[2], qz = q[3];
        float inv = 1.0f / (sqrtf(qw * qw + qx * qx + qy * qy + qz * qz) + 1e-12f);
        float* qp = (float*)(ws + QUAT_OFF) + (size_t)i * 4;
        qp[0] = qw * inv; qp[1] = qx * inv; qp[2] = qy * inv; qp[3] = qz * inv;
    }
}

// One thread = one (b, point): all 3 k's, reflect+rotate => 6 gathers in
// flight. Per-XCD block ordering walks b's sequentially (xcd = blockIdx & 7)
// so each cp slice is gathered while L2-resident. Transform params are
// precomputed (no div/sqrt here). Final reduction fused via last-block-done.
__global__ __launch_bounds__(256, 8) void symloss_main(
    const float* __restrict__ points, const float* __restrict__ cp,
    char* __restrict__ ws, float* __restrict__ out) {
    float2* partials = (float2*)ws;
    unsigned* ctr = (unsigned*)(ws + CTR_OFF);
    const float* refl_p = (const float*)(ws + REFL_OFF);
    const float* quat_p = (const float*)(ws + QUAT_OFF);

    int raw = blockIdx.x;
    int xcd = raw & 7;
    int s   = raw >> 3;                   // 0..511 per XCD
    int b   = xcd * B_PER_XCD + s / BLOCKS_PER_B;
    int chunk = s % BLOCKS_PER_B;         // 0..31
    int n = chunk * 256 + threadIdx.x;

    const float* p = points + ((size_t)b * NN + n) * 3;
    float px = p[0], py = p[1], pz = p[2];
    const float* cpb = cp + (size_t)b * SLICE_FLOATS;

    float tx[2 * KK], ty[2 * KK], tz[2 * KK];

#pragma unroll
    for (int k = 0; k < KK; ++k) {
        int i = k * BB + b;               // uniform per block -> scalar loads
        const float* rp = refl_p + (size_t)i * 8;
        float nx = rp[0], ny = rp[1], nz = rp[2], d = rp[3];
        float mx = rp[4], my = rp[5], mz = rp[6];
        float t = px * nx + py * ny + pz * nz + d;
        tx[k] = px - t * mx;
        ty[k] = py - t * my;
        tz[k] = pz - t * mz;

        const float* qp = quat_p + (size_t)i * 4;
        float qw = qp[0], qx = qp[1], qy = qp[2], qz = qp[3];
        float ux = qy * pz - qz * py;
        float uy = qz * px - qx * pz;
        float uz = qx * py - qy * px;
        float sx = ux + qw * px;
        float sy = uy + qw * py;
        float sz = uz + qw * pz;
        tx[KK + k] = px + 2.0f * (qy * sz - qz * sy);
        ty[KK + k] = py + 2.0f * (qz * sx - qx * sz);
        tz[KK + k] = pz + 2.0f * (qx * sy - qy * sx);
    }

    int flat[2 * KK];
#pragma unroll
    for (int i = 0; i < 2 * KK; ++i) {
        float fx = fminf(fmaxf(floorf((tx[i] + 0.5f) * 64.0f), 0.0f), 63.0f);
        float fy = fminf(fmaxf(floorf((ty[i] + 0.5f) * 64.0f), 0.0f), 63.0f);
        float fz = fminf(fmaxf(floorf((tz[i] + 0.5f) * 64.0f), 0.0f), 63.0f);
        flat[i] = (((int)fx * GS) + (int)fy) * GS + (int)fz;
    }

    float cx[2 * KK], cy[2 * KK], cz[2 * KK];
#pragma unroll
    for (int i = 0; i < 2 * KK; ++i) {
        const float* c = cpb + (size_t)flat[i] * 3;
        cx[i] = c[0];
        cy[i] = c[1];
        cz[i] = c[2];
    }

    float ref_acc = 0.0f, rot_acc = 0.0f;
#pragma unroll
    for (int i = 0; i < KK; ++i) {
        float dx = tx[i] - cx[i], dy = ty[i] - cy[i], dz = tz[i] - cz[i];
        ref_acc += dx * dx + dy * dy + dz * dz;
    }
#pragma unroll
    for (int i = KK; i < 2 * KK; ++i) {
        float dx = tx[i] - cx[i], dy = ty[i] - cy[i], dz = tz[i] - cz[i];
        rot_acc += dx * dx + dy * dy + dz * dz;
    }

    for (int off = 32; off > 0; off >>= 1) {
        ref_acc += __shfl_down(ref_acc, off, 64);
        rot_acc += __shfl_down(rot_acc, off, 64);
    }
    __shared__ float s_ref[4], s_rot[4];
    int wave = threadIdx.x >> 6;
    int lane = threadIdx.x & 63;
    if (lane == 0) {
        s_ref[wave] = ref_acc;
        s_rot[wave] = rot_acc;
    }
    __syncthreads();

    __shared__ int is_last;
    if (threadIdx.x == 0) {
        float2 v;
        v.x = s_ref[0] + s_ref[1] + s_ref[2] + s_ref[3];
        v.y = s_rot[0] + s_rot[1] + s_rot[2] + s_rot[3];
        partials[blockIdx.x] = v;
        __threadfence();                       // release partial
        unsigned old = atomicAdd(ctr, 1u);     // device scope
        is_last = (old == (unsigned)(GRID - 1));
    }
    __syncthreads();

    if (is_last) {
        __threadfence();                       // acquire others' partials
        double r = 0.0, o = 0.0;
        for (int i = threadIdx.x; i < GRID; i += 256) {
            float2 v = partials[i];
            r += (double)v.x;
            o += (double)v.y;
        }
        __shared__ double d_r[256], d_o[256];
        d_r[threadIdx.x] = r;
        d_o[threadIdx.x] = o;
        __syncthreads();
        for (int off = 128; off > 0; off >>= 1) {
            if (threadIdx.x < off) {
                d_r[threadIdx.x] += d_r[threadIdx.x + off];
                d_o[threadIdx.x] += d_o[threadIdx.x + off];
            }
            __syncthreads();
        }
        if (threadIdx.x == 0) {
            const double inv = 1.0 / ((double)BB * (double)NN);
            out[0] = (float)(d_r[0] * inv);
            out[1] = (float)(d_o[0] * inv);
        }
    }
}

extern "C" void kernel_launch(void* const* d_in, const int* in_sizes, int n_in,
                              void* d_out, int out_size, void* d_ws, size_t ws_size,
                              hipStream_t stream) {
    const float* points = (const float*)d_in[0];
    const float* cp     = (const float*)d_in[1];
    // d_in[2] = voxel (unused)
    const float* plane  = (const float*)d_in[3];
    const float* quat   = (const float*)d_in[4];
    float* out = (float*)d_out;
    char* ws = (char*)d_ws;

    init_kernel<<<1, 384, 0, stream>>>(plane, quat, ws);
    symloss_main<<<GRID, 256, 0, stream>>>(points, cp, ws, out);
}

// Round 10
// 65.003 us; speedup vs baseline: 4.1106x; 4.1106x over previous
//
#include <hip/hip_runtime.h>

#define GS 64
#define BB 128
#define NN 8192
#define KK 3
#define SLICE_FLOATS (GS * GS * GS * 3)   // 786432 floats = 3 MB per b
#define B_PER_XCD 16
#define BLOCKS_PER_B 32                   // 32 chunks of 256 pts; all k per thread
#define GRID (BB * BLOCKS_PER_B)          // 4096

// One thread = one (b, point): all 3 k's, reflect+rotate => 6 independent
// gathers in flight. Per-XCD block ordering walks b's sequentially
// (xcd = blockIdx & 7 round-robin) keeping the live b-window small =>
// L2/L3-resident gathers. NO device-scope fences/atomics anywhere in the hot
// path (rounds 4/7/9 showed they destroy L2 residency / serialize).
__global__ __launch_bounds__(256, 8) void symloss_main(
    const float* __restrict__ points, const float* __restrict__ cp,
    const float* __restrict__ plane, const float* __restrict__ quat,
    float2* __restrict__ partials) {
    int raw = blockIdx.x;
    int xcd = raw & 7;
    int s   = raw >> 3;                   // 0..511 per XCD
    int b   = xcd * B_PER_XCD + s / BLOCKS_PER_B;
    int chunk = s % BLOCKS_PER_B;         // 0..31
    int n = chunk * 256 + threadIdx.x;

    const float* p = points + ((size_t)b * NN + n) * 3;
    float px = p[0], py = p[1], pz = p[2];
    const float* cpb = cp + (size_t)b * SLICE_FLOATS;

    // transformed coords for all 6 streams: [0..2] reflect, [3..5] rotate
    float tx[2 * KK], ty[2 * KK], tz[2 * KK];

#pragma unroll
    for (int k = 0; k < KK; ++k) {
        // ---- reflect (b,k uniform per block -> scalar loads) ----
        const float* plk = plane + ((size_t)k * BB + b) * 4;
        float nx = plk[0], ny = plk[1], nz = plk[2], d = plk[3];
        float denom = nx * nx + ny * ny + nz * nz + 1e-12f;
        float tt = (px * nx + py * ny + pz * nz + d) / denom;
        tx[k] = px - 2.0f * tt * nx;
        ty[k] = py - 2.0f * tt * ny;
        tz[k] = pz - 2.0f * tt * nz;

        // ---- rotate ----
        const float* q = quat + ((size_t)k * BB + b) * 4;
        float qw = q[0], qx = q[1], qy = q[2], qz = q[3];
        float qn = sqrtf(qw * qw + qx * qx + qy * qy + qz * qz) + 1e-12f;
        qw /= qn; qx /= qn; qy /= qn; qz /= qn;
        float ux = qy * pz - qz * py;
        float uy = qz * px - qx * pz;
        float uz = qx * py - qy * px;
        float sx = ux + qw * px;
        float sy = uy + qw * py;
        float sz = uz + qw * pz;
        tx[KK + k] = px + 2.0f * (qy * sz - qz * sy);
        ty[KK + k] = py + 2.0f * (qz * sx - qx * sz);
        tz[KK + k] = pz + 2.0f * (qx * sy - qy * sx);
    }

    // ---- all 6 flat indices first (ints, saves VGPRs) ----
    int flat[2 * KK];
#pragma unroll
    for (int i = 0; i < 2 * KK; ++i) {
        float fx = fminf(fmaxf(floorf((tx[i] + 0.5f) * 64.0f), 0.0f), 63.0f);
        float fy = fminf(fmaxf(floorf((ty[i] + 0.5f) * 64.0f), 0.0f), 63.0f);
        float fz = fminf(fmaxf(floorf((tz[i] + 0.5f) * 64.0f), 0.0f), 63.0f);
        flat[i] = (((int)fx * GS) + (int)fy) * GS + (int)fz;
    }

    // ---- issue all 6 gathers back-to-back, then consume ----
    float cx[2 * KK], cy[2 * KK], cz[2 * KK];
#pragma unroll
    for (int i = 0; i < 2 * KK; ++i) {
        const float* c = cpb + (size_t)flat[i] * 3;
        cx[i] = c[0];
        cy[i] = c[1];
        cz[i] = c[2];
    }

    float ref_acc = 0.0f, rot_acc = 0.0f;
#pragma unroll
    for (int i = 0; i < KK; ++i) {
        float dx = tx[i] - cx[i], dy = ty[i] - cy[i], dz = tz[i] - cz[i];
        ref_acc += dx * dx + dy * dy + dz * dz;
    }
#pragma unroll
    for (int i = KK; i < 2 * KK; ++i) {
        float dx = tx[i] - cx[i], dy = ty[i] - cy[i], dz = tz[i] - cz[i];
        rot_acc += dx * dx + dy * dy + dz * dz;
    }

    // ---- block reduction: shuffle (width 64) -> LDS -> one plain store ----
    for (int off = 32; off > 0; off >>= 1) {
        ref_acc += __shfl_down(ref_acc, off, 64);
        rot_acc += __shfl_down(rot_acc, off, 64);
    }
    __shared__ float s_ref[4], s_rot[4];
    int wave = threadIdx.x >> 6;
    int lane = threadIdx.x & 63;
    if (lane == 0) {
        s_ref[wave] = ref_acc;
        s_rot[wave] = rot_acc;
    }
    __syncthreads();
    if (threadIdx.x == 0) {
        float2 v;
        v.x = s_ref[0] + s_ref[1] + s_ref[2] + s_ref[3];
        v.y = s_rot[0] + s_rot[1] + s_rot[2] + s_rot[3];
        partials[blockIdx.x] = v;   // distinct slot per block, no atomics
    }
}

// Lean finalize: 256 threads, float4 loads (2 partials each), double
// accumulation, wave shuffle reduce -> 4 LDS slots -> serial sum of 4.
__global__ __launch_bounds__(256) void finalize_kernel(
    const float4* __restrict__ partials4, float* __restrict__ out) {
    double r = 0.0, o = 0.0;
    // GRID/2 = 2048 float4's, 256 threads -> 8 iterations
    for (int i = threadIdx.x; i < GRID / 2; i += 256) {
        float4 v = partials4[i];
        r += (double)v.x + (double)v.z;
        o += (double)v.y + (double)v.w;
    }
    for (int off = 32; off > 0; off >>= 1) {
        r += __shfl_down(r, off, 64);
        o += __shfl_down(o, off, 64);
    }
    __shared__ double s_r[4], s_o[4];
    int wave = threadIdx.x >> 6;
    int lane = threadIdx.x & 63;
    if (lane == 0) {
        s_r[wave] = r;
        s_o[wave] = o;
    }
    __syncthreads();
    if (threadIdx.x == 0) {
        const double inv = 1.0 / ((double)BB * (double)NN);
        out[0] = (float)((s_r[0] + s_r[1] + s_r[2] + s_r[3]) * inv);
        out[1] = (float)((s_o[0] + s_o[1] + s_o[2] + s_o[3]) * inv);
    }
}

extern "C" void kernel_launch(void* const* d_in, const int* in_sizes, int n_in,
                              void* d_out, int out_size, void* d_ws, size_t ws_size,
                              hipStream_t stream) {
    const float* points = (const float*)d_in[0];
    const float* cp     = (const float*)d_in[1];
    // d_in[2] = voxel (unused)
    const float* plane  = (const float*)d_in[3];
    const float* quat   = (const float*)d_in[4];
    float* out = (float*)d_out;
    float2* partials = (float2*)d_ws;     // 4096 * 8 B = 32 KB

    symloss_main<<<GRID, 256, 0, stream>>>(points, cp, plane, quat, partials);
    finalize_kernel<<<1, 256, 0, stream>>>((const float4*)partials, out);
}